// Round 9
// baseline (477.202 us; speedup 1.0000x reference)
//
#include <hip/hip_runtime.h>
#include <hip/hip_bf16.h>
#include <stdint.h>

// GAT forward, N=8192, IN=256, OUT=128. Inputs fp32 (adj int32), output fp32.
// softmax_j(a1_i + a2_j | adj) == adj_ij*exp(a2_j)/sum_j adj_ij*exp(a2_j)  (a1 cancels)
// -> out = (adj @ (w*h)) / (adj @ w).
// k_agg v6: two-phase. Phase 1: block streams its 32 adj rows (1 MB, pure MLP,
// no MFMA dependency) -> 1-bit/elem LDS bitmask (33 KB, stride-260 words = 2-way
// bank alias only). Phase 2: K-loop A = ds_read_b32 + 10-VALU bit->bf16 expand;
// B = whT global (L2-resident now that the adj stream no longer thrashes L2).
// Kills the R5/7/8 ~175us wall (serialized 250-cyc loads: 52 VGPRs couldn't
// hold 13 in-flight results).

typedef __attribute__((ext_vector_type(8))) short short8;
typedef __attribute__((ext_vector_type(4))) float float4v;

static __device__ __forceinline__ unsigned short f2bf(float f) {
    union { float f; uint32_t i; } v; v.f = f;
    uint32_t r = v.i + 0x7FFFu + ((v.i >> 16) & 1u);
    return (unsigned short)(r >> 16);
}

// expand low 8 bits of t -> 8 packed bf16 {0.0, 1.0}
static __device__ __forceinline__ short8 expand8(uint32_t t) {
    union { uint32_t u[4]; short8 s; } v;
    #pragma unroll
    for (int p = 0; p < 4; p++) {
        uint32_t q = t >> (2 * p);
        v.u[p] = (q & 1u) * 0x3F80u | (q & 2u) * 0x1FC00000u;
    }
    return v.s;
}

// ---- WT[n][k] = bf16(W[k][n]) : 128x256 k-major ----
__global__ void k_transpose_w(const float* __restrict__ W, unsigned short* __restrict__ WT) {
    __shared__ unsigned short tile[32][33];
    int tx = threadIdx.x & 31, ty = threadIdx.x >> 5;
    int n0 = blockIdx.x * 32, k0 = blockIdx.y * 32;
    for (int i = 0; i < 4; i++)
        tile[ty + 8 * i][tx] = f2bf(W[(k0 + ty + 8 * i) * 128 + n0 + tx]);
    __syncthreads();
    for (int i = 0; i < 4; i++)
        WT[(size_t)(n0 + ty + 8 * i) * 256 + k0 + tx] = tile[tx][ty + 8 * i];
}

// ---- fused: h = F@W+b (MFMA) -> w = exp(h.a2w+a2b) -> whT rows 0..128 ----
__global__ __launch_bounds__(256) void k_h_fused(const float* __restrict__ F,
                                                 const unsigned short* __restrict__ WT,
                                                 const float* __restrict__ bvec,
                                                 const float* __restrict__ a2w,
                                                 const float* __restrict__ a2b,
                                                 unsigned short* __restrict__ whT) {
    __shared__ __align__(16) unsigned short As[64 * 72];
    __shared__ __align__(16) unsigned short Bs[128 * 72];
    __shared__ __align__(16) unsigned short T[129 * 72];   // [col][row_local]
    __shared__ float bs[128], aw[128], ab_s;

    int t = threadIdx.x, lane = t & 63, wave = t >> 6;
    int rb = blockIdx.x * 64;
    if (t < 128) { bs[t] = bvec[t]; aw[t] = a2w[t]; }
    if (t == 0) ab_s = a2b[0];

    float4v acc[8];
    for (int c = 0; c < 8; c++) acc[c] = (float4v)0.0f;

    for (int kt = 0; kt < 4; kt++) {
        int k0 = kt * 64;
        for (int i = 0; i < 2; i++) {                       // A: 64x64 fp32 -> bf16
            int flat = t + 256 * i, row = flat >> 3, part = flat & 7;
            const float* fp = F + (size_t)(rb + row) * 256 + k0 + part * 8;
            float4 v0 = *reinterpret_cast<const float4*>(fp);
            float4 v1 = *reinterpret_cast<const float4*>(fp + 4);
            uint4 v;
            v.x = f2bf(v0.x) | ((uint32_t)f2bf(v0.y) << 16);
            v.y = f2bf(v0.z) | ((uint32_t)f2bf(v0.w) << 16);
            v.z = f2bf(v1.x) | ((uint32_t)f2bf(v1.y) << 16);
            v.w = f2bf(v1.z) | ((uint32_t)f2bf(v1.w) << 16);
            *reinterpret_cast<uint4*>(&As[row * 72 + part * 8]) = v;
        }
        for (int i = 0; i < 4; i++) {                       // B: 128x64 bf16 k-major
            int flat = t + 256 * i, n = flat >> 3, part = flat & 7;
            *reinterpret_cast<uint4*>(&Bs[n * 72 + part * 8]) =
                *reinterpret_cast<const uint4*>(WT + (size_t)n * 256 + k0 + part * 8);
        }
        __syncthreads();
        int m = lane & 15, kq = lane >> 4;
        for (int ks = 0; ks < 2; ks++) {
            short8 af = *reinterpret_cast<const short8*>(&As[(wave * 16 + m) * 72 + ks * 32 + kq * 8]);
            for (int c = 0; c < 8; c++) {
                short8 bfr = *reinterpret_cast<const short8*>(&Bs[(c * 16 + m) * 72 + ks * 32 + kq * 8]);
                acc[c] = __builtin_amdgcn_mfma_f32_16x16x32_bf16(af, bfr, acc[c], 0, 0, 0);
            }
        }
        __syncthreads();
    }

    int m = lane & 15, kq = lane >> 4;
    float hv[8][4], part[4];
    for (int r = 0; r < 4; r++) part[r] = 0.0f;
    for (int c = 0; c < 8; c++) {
        float bb = bs[c * 16 + m], a = aw[c * 16 + m];
        for (int r = 0; r < 4; r++) { hv[c][r] = acc[c][r] + bb; part[r] += hv[c][r] * a; }
    }
    for (int off = 1; off < 16; off <<= 1)
        for (int r = 0; r < 4; r++) part[r] += __shfl_xor(part[r], off, 64);
    float wr[4];
    for (int r = 0; r < 4; r++) {
        float e = fminf(fmaxf(part[r] + ab_s, -60.0f), 60.0f);
        wr[r] = expf(e);
    }
    int rl = wave * 16 + kq * 4;
    for (int c = 0; c < 8; c++)
        for (int r = 0; r < 4; r++)
            T[(c * 16 + m) * 72 + rl + r] = f2bf(hv[c][r] * wr[r]);
    if (m == 0)
        for (int r = 0; r < 4; r++)
            T[128 * 72 + rl + r] = f2bf(wr[r]);
    __syncthreads();

    for (int i = 0; i < 5; i++) {                           // 129 rows x 64 shorts
        int flat = t + 256 * i;
        if (flat < 1032) {
            int row = flat >> 3, part = flat & 7;
            *reinterpret_cast<uint4*>(whT + (size_t)row * 8192 + rb + part * 8) =
                *reinterpret_cast<const uint4*>(&T[row * 72 + part * 8]);
        }
    }
}

// ---- KMAIN: out[32 rows] = (adj @ wh) / (adj @ w). Two-phase per block. ----
#define BM_STRIDE 260   // words; 260 = 8*32+4 -> lanes m,m+8 alias a bank (2-way, free)
__global__ __launch_bounds__(512, 2) void k_agg(const int* __restrict__ adj,
                                                const unsigned short* __restrict__ whT,
                                                float* __restrict__ out) {
    __shared__ uint32_t bmL[32 * BM_STRIDE];   // 33,280 B  (32 rows x 8192 bits)
    __shared__ float red[32][148];             // 18,944 B
    int t = threadIdx.x, lane = t & 63, wave = t >> 6;   // 8 waves
    int m = lane & 15, kq = lane >> 4;
    int rb = blockIdx.x * 32;

    // ---- phase 1: pack this block's 32 adj rows into the LDS bitmask ----
    #pragma unroll
    for (int i = 0; i < 16; i++) {
        int w = t + i * 512;                   // 0..8191 : row = w>>8, 32-col group = w&255
        int row = w >> 8, c32 = w & 255;
        const int* p = adj + (size_t)(rb + row) * 8192 + c32 * 32;
        uint32_t word = 0;
        #pragma unroll
        for (int j = 0; j < 8; j++) {
            int4 v = *reinterpret_cast<const int4*>(p + j * 4);
            word |= (uint32_t)(v.x & 1) << (4 * j)     | (uint32_t)(v.y & 1) << (4 * j + 1)
                  | (uint32_t)(v.z & 1) << (4 * j + 2) | (uint32_t)(v.w & 1) << (4 * j + 3);
        }
        bmL[row * BM_STRIDE + c32] = word;
    }
    __syncthreads();

    // ---- phase 2: K-loop. wave covers K in [wave*1024, wave*1024+1024). ----
    float4v acc[2][9];
    #pragma unroll
    for (int s = 0; s < 2; s++)
        for (int c = 0; c < 9; c++) acc[s][c] = (float4v)0.0f;

    const uint32_t* bm0 = &bmL[m * BM_STRIDE + wave * 32];
    const uint32_t* bm1 = &bmL[(m + 16) * BM_STRIDE + wave * 32];
    const unsigned short* bp = whT + (size_t)m * 8192 + wave * 1024 + kq * 8;
    int sh = kq * 8;

    #pragma unroll 2
    for (int it = 0; it < 32; ++it) {
        uint32_t W0 = bm0[it], W1 = bm1[it];
        short8 af0 = expand8(W0 >> sh);
        short8 af1 = expand8(W1 >> sh);
        const unsigned short* bk = bp + it * 32;
        #pragma unroll
        for (int c = 0; c < 9; c++) {
            short8 bf = *reinterpret_cast<const short8*>(bk + (size_t)c * 131072);
            acc[0][c] = __builtin_amdgcn_mfma_f32_16x16x32_bf16(af0, bf, acc[0][c], 0, 0, 0);
            acc[1][c] = __builtin_amdgcn_mfma_f32_16x16x32_bf16(af1, bf, acc[1][c], 0, 0, 0);
        }
    }

    // ---- LDS reduction across the 8 waves ----
    for (int i = t; i < 32 * 148; i += 512)
        (&red[0][0])[i] = 0.0f;
    __syncthreads();
    for (int w = 0; w < 8; w++) {
        if (wave == w) {
            #pragma unroll
            for (int s = 0; s < 2; s++)
                for (int c = 0; c < 9; c++)
                    for (int rr = 0; rr < 4; rr++)
                        red[s * 16 + kq * 4 + rr][c * 16 + m] += acc[s][c][rr];
        }
        __syncthreads();
    }

    // ---- fused epilogue: out = num / den ----
    for (int i = t; i < 32 * 128; i += 512) {
        int r = i >> 7, c = i & 127;
        out[(size_t)(rb + r) * 128 + c] = red[r][c] / red[r][128];
    }
}

extern "C" void kernel_launch(void* const* d_in, const int* in_sizes, int n_in,
                              void* d_out, int out_size, void* d_ws, size_t ws_size,
                              hipStream_t stream) {
    const float* F   = (const float*)d_in[0];     // [8192][256]
    const int*   adj = (const int*)d_in[1];       // [8192][8192] 0/1
    const float* W   = (const float*)d_in[2];     // [256][128]
    const float* bv  = (const float*)d_in[3];     // [128]
    const float* a2w = (const float*)d_in[6];     // [128]  (a1 cancels; d_in[4],[5] unused)
    const float* a2b = (const float*)d_in[7];     // [1]
    float* out = (float*)d_out;                   // [8192][128]

    char* ws = (char*)d_ws;
    unsigned short* whT = (unsigned short*)(ws);            // 2,359,296 B (144 x 8192 bf16)
    unsigned short* WT  = (unsigned short*)(ws + 2359296);  //    65,536 B  (total 2.42 MB)

    k_transpose_w<<<dim3(4, 8), 256, 0, stream>>>(W, WT);
    k_h_fused<<<128, 256, 0, stream>>>(F, WT, bv, a2w, a2b, whT);
    k_agg<<<256, 512, 0, stream>>>(adj, whT, out);
}